// Round 2
// baseline (336.378 us; speedup 1.0000x reference)
//
#include <hip/hip_runtime.h>
#include <hip/hip_bf16.h>
#include <math.h>
#include <stdint.h>

typedef __bf16 bf16_t;
typedef __bf16 bf16x4v __attribute__((ext_vector_type(4)));
typedef __bf16 bf16x8 __attribute__((ext_vector_type(8)));
typedef float  f32x4  __attribute__((ext_vector_type(4)));

#define L_LEN 8192
#define MODES 64
#define NCOMP 128      // 2*MODES (Re | Im)
#define M_ROWS 4096    // B * n_env * ch

// ---------------------------------------------------------------------------
// Basis tables. Phase is exact: (k*l) mod 8192, angle = r/8192 revolutions,
// fed straight to v_cos/v_sin (hardware takes revolutions). bf16 rounding
// dominates error; HW trig delta (~1e-6) is negligible.
// B1 [l][c] : c<64 -> cos, c>=64 -> -sin   [8192][128]  (stage2 operand)
// B1t[c][l] : transposed                    [128][8192]  (stage1 operand)
// ---------------------------------------------------------------------------
__global__ void gen_b1(bf16_t* __restrict__ B1) {
  int id = blockIdx.x * 256 + threadIdx.x;   // 8192*64 threads
  int l = id >> 6;
  int k = id & 63;
  float fr = (float)((l * k) & (L_LEN - 1)) * (1.0f / 8192.0f);
  float c = __builtin_amdgcn_cosf(fr);
  float s = __builtin_amdgcn_sinf(fr);
  B1[l * NCOMP + k]         = (bf16_t)c;     // lanes: adjacent k -> coalesced
  B1[l * NCOMP + MODES + k] = (bf16_t)(-s);
}

__global__ void gen_b1t(bf16_t* __restrict__ B1t) {
  int id = blockIdx.x * 256 + threadIdx.x;   // 64*2048 threads
  int k  = id >> 11;
  int l0 = (id & 2047) * 4;                  // 4 consecutive l per thread
  bf16x4v cv, sv;
#pragma unroll
  for (int j = 0; j < 4; ++j) {
    float fr = (float)(((l0 + j) * k) & (L_LEN - 1)) * (1.0f / 8192.0f);
    cv[j] = (bf16_t)__builtin_amdgcn_cosf(fr);
    sv[j] = (bf16_t)(-__builtin_amdgcn_sinf(fr));
  }
  *(bf16x4v*)(B1t + (size_t)k * L_LEN + l0)        = cv;  // 8B x 64 lanes contiguous
  *(bf16x4v*)(B1t + (size_t)(k + 64) * L_LEN + l0) = sv;
}

// ---------------------------------------------------------------------------
// W[e][i][o][k] (complex fp32) = lam[k]*cw[i][o][k] + (1-lam[k])*codes[e]@codew[.][i][o][k]
// ---------------------------------------------------------------------------
__global__ void wmix(const float* __restrict__ codes, const float* __restrict__ comw,
                     const float* __restrict__ codew, const float* __restrict__ fw,
                     float* __restrict__ W) {
  int id = blockIdx.x * 256 + threadIdx.x;   // 8*32*32*64 threads
  int k = id & 63;
  int o = (id >> 6) & 31;
  int i = (id >> 11) & 31;
  int e = id >> 16;
  float lam = fminf(fmaxf(fw[k] * (1.0f / 6.0f) + 0.5f, 0.0f), 1.0f);
  float are = 0.f, aim = 0.f;
#pragma unroll
  for (int c = 0; c < 16; ++c) {
    float cd = codes[e * 16 + c];
    const float* p = codew + ((((c * 32 + i) * 32 + o) * 64 + k) << 1);
    are += cd * p[0];
    aim += cd * p[1];
  }
  const float* q = comw + (((i * 32 + o) * 64 + k) << 1);
  float wre = lam * q[0] + (1.f - lam) * are;
  float wim = lam * q[1] + (1.f - lam) * aim;
  float* dst = W + ((((e * 32 + i) * 32 + o) * 64 + k) << 1);
  dst[0] = wre;
  dst[1] = wim;
}

// ---------------------------------------------------------------------------
// Stage 1: X[4096][128] += x[4096][8192] * B1t^T  -- LDS-free, barrier-free.
// grid = (64 m-tiles of 64 rows, 16 k-splits of 512). Block = 4 waves,
// wave tile 32m x 64n: wm=w>>1 (m-half), wn=w&1 (n-half).
// A-frag: lane reads 32B contiguous fp32 from x, cvt->bf16 (x streamed once).
// B-frag: lane reads 16B from B1t (2 MB, L2-resident).
// Split-K reduced via fp32 atomicAdd into pre-zeroed X.
// ---------------------------------------------------------------------------
__global__ __launch_bounds__(256) void stage1(const float* __restrict__ x,
                                              const bf16_t* __restrict__ B1t,
                                              float* __restrict__ X) {
  const int t = threadIdx.x;
  const int lane = t & 63;
  const int w = t >> 6;
  const int wm = w >> 1, wn = w & 1;
  const int mt = blockIdx.x;
  const int sp = blockIdx.y;
  const int lq = lane >> 4, l15 = lane & 15;
  const int mbase = mt * 64 + wm * 32;

  f32x4 acc[2][4];
#pragma unroll
  for (int a = 0; a < 2; ++a)
#pragma unroll
    for (int b = 0; b < 4; ++b) acc[a][b] = (f32x4){0.f, 0.f, 0.f, 0.f};

  const float*  xr0 = x + (size_t)(mbase + l15) * L_LEN + lq * 8;
  const bf16_t* bp0 = B1t + (size_t)(wn * 64 + l15) * L_LEN + lq * 8;

#pragma unroll 2
  for (int ks = 0; ks < 16; ++ks) {
    const int k0 = sp * 512 + ks * 32;
    bf16x8 a[2];
#pragma unroll
    for (int mf = 0; mf < 2; ++mf) {
      const float4* ap = (const float4*)(xr0 + (size_t)mf * 16 * L_LEN + k0);
      float4 p0 = ap[0], p1 = ap[1];
      a[mf] = (bf16x8){(bf16_t)p0.x, (bf16_t)p0.y, (bf16_t)p0.z, (bf16_t)p0.w,
                       (bf16_t)p1.x, (bf16_t)p1.y, (bf16_t)p1.z, (bf16_t)p1.w};
    }
    bf16x8 b[4];
#pragma unroll
    for (int nf = 0; nf < 4; ++nf)
      b[nf] = *(const bf16x8*)(bp0 + (size_t)nf * 16 * L_LEN + k0);
#pragma unroll
    for (int mf = 0; mf < 2; ++mf)
#pragma unroll
      for (int nf = 0; nf < 4; ++nf)
        acc[mf][nf] = __builtin_amdgcn_mfma_f32_16x16x32_bf16(a[mf], b[nf], acc[mf][nf], 0, 0, 0);
  }

#pragma unroll
  for (int mf = 0; mf < 2; ++mf)
#pragma unroll
    for (int nf = 0; nf < 4; ++nf) {
      int n = wn * 64 + nf * 16 + l15;
#pragma unroll
      for (int rg = 0; rg < 4; ++rg) {
        int m = mbase + mf * 16 + lq * 4 + rg;   // C frag: row=(lane>>4)*4+reg, col=lane&15
        atomicAdd(X + (size_t)m * NCOMP + n, acc[mf][nf][rg]);
      }
    }
}

// ---------------------------------------------------------------------------
// Mix: per (b,e) block. Y[b,e,o,k] = sum_i X[b,e,i,k]*W[e,i,o,k], irfft-scaled,
// emitted as bf16 A2[m=(b,e,o)][Re k | Im k].
// ---------------------------------------------------------------------------
__global__ __launch_bounds__(256) void mixk(const float* __restrict__ X,
                                            const float* __restrict__ W,
                                            bf16_t* __restrict__ A2) {
  __shared__ float Xs[32 * 128];
  const int t = threadIdx.x;
  const int be = blockIdx.x;       // b*8+e
  const int e = be & 7;
#pragma unroll
  for (int j = 0; j < 16; ++j) {
    int idx = t + 256 * j;
    Xs[idx] = X[(size_t)be * 4096 + idx];
  }
  __syncthreads();
  const int k = t & 63;
  const int olo = t >> 6;          // o = olo*8 + j
  float yre[8], yim[8];
#pragma unroll
  for (int j = 0; j < 8; ++j) { yre[j] = 0.f; yim[j] = 0.f; }
  for (int i = 0; i < 32; ++i) {
    float xr = Xs[i * 128 + k];
    float xi = Xs[i * 128 + 64 + k];
    const float* wp = W + ((((e * 32 + i) * 32 + olo * 8) * 64 + k) << 1);
#pragma unroll
    for (int j = 0; j < 8; ++j) {
      float2 wv = *(const float2*)(wp + j * 128);
      yre[j] += xr * wv.x - xi * wv.y;
      yim[j] += xr * wv.y + xi * wv.x;
    }
  }
  float sc = (k == 0) ? (1.0f / 8192.0f) : (2.0f / 8192.0f);  // irfft: DC 1/L, others 2/L
#pragma unroll
  for (int j = 0; j < 8; ++j) {
    int m = be * 32 + olo * 8 + j;
    A2[m * NCOMP + k]         = (bf16_t)(yre[j] * sc);
    A2[m * NCOMP + MODES + k] = (bf16_t)(yim[j] * sc);
  }
}

// ---------------------------------------------------------------------------
// Stage 2: out[4096][8192] = A2[4096][128] * B1^T -- LDS-free, barrier-free.
// grid = (64 l-tiles, 32 m-tiles). Block = 4 waves, wave tile 64m x 64l.
// Both operands read directly from global (A2 1 MB + B1 2 MB, L2-resident).
// ---------------------------------------------------------------------------
__global__ __launch_bounds__(256) void stage2(const bf16_t* __restrict__ A2,
                                              const bf16_t* __restrict__ B1,
                                              float* __restrict__ out) {
  const int t = threadIdx.x;
  const int lane = t & 63;
  const int w = t >> 6;
  const int wm = w >> 1, wl = w & 1;
  const int lt = blockIdx.x, mt = blockIdx.y;
  const int lq = lane >> 4, l15 = lane & 15;

  f32x4 acc[4][4];
#pragma unroll
  for (int a = 0; a < 4; ++a)
#pragma unroll
    for (int b = 0; b < 4; ++b) acc[a][b] = (f32x4){0.f, 0.f, 0.f, 0.f};

  const bf16_t* ap0 = A2 + (size_t)(mt * 128 + wm * 64 + l15) * NCOMP + lq * 8;
  const bf16_t* bp0 = B1 + (size_t)(lt * 128 + wl * 64 + l15) * NCOMP + lq * 8;

#pragma unroll 2
  for (int s = 0; s < 4; ++s) {
    bf16x8 a[4], b[4];
#pragma unroll
    for (int mf = 0; mf < 4; ++mf)
      a[mf] = *(const bf16x8*)(ap0 + mf * 16 * NCOMP + s * 32);
#pragma unroll
    for (int nf = 0; nf < 4; ++nf)
      b[nf] = *(const bf16x8*)(bp0 + nf * 16 * NCOMP + s * 32);
#pragma unroll
    for (int mf = 0; mf < 4; ++mf)
#pragma unroll
      for (int nf = 0; nf < 4; ++nf)
        acc[mf][nf] = __builtin_amdgcn_mfma_f32_16x16x32_bf16(a[mf], b[nf], acc[mf][nf], 0, 0, 0);
  }

#pragma unroll
  for (int mf = 0; mf < 4; ++mf)
#pragma unroll
    for (int nf = 0; nf < 4; ++nf) {
      int m = mt * 128 + wm * 64 + mf * 16 + lq * 4;
      int l = lt * 128 + wl * 64 + nf * 16 + l15;
      float* op = out + (size_t)m * L_LEN + l;
#pragma unroll
      for (int rg = 0; rg < 4; ++rg) op[(size_t)rg * L_LEN] = acc[mf][nf][rg];
    }
}

// ---------------------------------------------------------------------------
// ws layout:  [0,2M) B1t bf16 [128][8192]
//             [2M,4M) B1 bf16 [8192][128]
//             [4M,6M) X fp32 [4096][128]
//             [6M,10M) W fp32 [8][32][32][64][2]
//             [10M,11M) A2 bf16 [4096][128]
// ---------------------------------------------------------------------------
extern "C" void kernel_launch(void* const* d_in, const int* in_sizes, int n_in,
                              void* d_out, int out_size, void* d_ws, size_t ws_size,
                              hipStream_t stream) {
  const float* x     = (const float*)d_in[0];
  const float* codes = (const float*)d_in[1];
  const float* comw  = (const float*)d_in[2];
  const float* codew = (const float*)d_in[3];
  const float* fw    = (const float*)d_in[4];
  float* out = (float*)d_out;
  char* ws = (char*)d_ws;
  bf16_t* B1t = (bf16_t*)(ws);
  bf16_t* B1  = (bf16_t*)(ws + (size_t)(2u << 20));
  float*  X   = (float*) (ws + (size_t)(4u << 20));
  float*  W   = (float*) (ws + (size_t)(6u << 20));
  bf16_t* A2  = (bf16_t*)(ws + (size_t)(10u << 20));

  gen_b1 <<<2048, 256, 0, stream>>>(B1);
  gen_b1t<<<512, 256, 0, stream>>>(B1t);
  wmix<<<2048, 256, 0, stream>>>(codes, comw, codew, fw, W);
  hipMemsetAsync(X, 0, (size_t)M_ROWS * NCOMP * sizeof(float), stream);
  stage1<<<dim3(64, 16), 256, 0, stream>>>(x, B1t, X);
  mixk<<<128, 256, 0, stream>>>(X, W, A2);
  stage2<<<dim3(64, 32), 256, 0, stream>>>(A2, B1, out);
}

// Round 3
// 327.349 us; speedup vs baseline: 1.0276x; 1.0276x over previous
//
#include <hip/hip_runtime.h>
#include <hip/hip_bf16.h>
#include <math.h>
#include <stdint.h>

typedef __bf16 bf16_t;
typedef __bf16 bf16x4v __attribute__((ext_vector_type(4)));
typedef __bf16 bf16x8 __attribute__((ext_vector_type(8)));
typedef float  f32x4  __attribute__((ext_vector_type(4)));

#define L_LEN 8192
#define MODES 64
#define NCOMP 128      // 2*MODES (Re | Im)
#define M_ROWS 4096    // B * n_env * ch
#define NSPLIT 8       // stage1 split-K slices

// ---------------------------------------------------------------------------
// Basis tables. Phase exact: (k*l) mod 8192, angle in revolutions for HW trig.
// B1 [l][c] : c<64 -> cos, c>=64 -> -sin   [8192][128]  (stage2 operand)
// B1t[c][l] : transposed                    [128][8192]  (stage1 operand)
// ---------------------------------------------------------------------------
__global__ void gen_b1(bf16_t* __restrict__ B1) {
  int id = blockIdx.x * 256 + threadIdx.x;   // 8192*64 threads
  int l = id >> 6;
  int k = id & 63;
  float fr = (float)((l * k) & (L_LEN - 1)) * (1.0f / 8192.0f);
  float c = __builtin_amdgcn_cosf(fr);
  float s = __builtin_amdgcn_sinf(fr);
  B1[l * NCOMP + k]         = (bf16_t)c;
  B1[l * NCOMP + MODES + k] = (bf16_t)(-s);
}

__global__ void gen_b1t(bf16_t* __restrict__ B1t) {
  int id = blockIdx.x * 256 + threadIdx.x;   // 64*2048 threads
  int k  = id >> 11;
  int l0 = (id & 2047) * 4;
  bf16x4v cv, sv;
#pragma unroll
  for (int j = 0; j < 4; ++j) {
    float fr = (float)(((l0 + j) * k) & (L_LEN - 1)) * (1.0f / 8192.0f);
    cv[j] = (bf16_t)__builtin_amdgcn_cosf(fr);
    sv[j] = (bf16_t)(-__builtin_amdgcn_sinf(fr));
  }
  *(bf16x4v*)(B1t + (size_t)k * L_LEN + l0)        = cv;
  *(bf16x4v*)(B1t + (size_t)(k + 64) * L_LEN + l0) = sv;
}

// ---------------------------------------------------------------------------
// W[e][i][o][k] (complex fp32)
// ---------------------------------------------------------------------------
__global__ void wmix(const float* __restrict__ codes, const float* __restrict__ comw,
                     const float* __restrict__ codew, const float* __restrict__ fw,
                     float* __restrict__ W) {
  int id = blockIdx.x * 256 + threadIdx.x;   // 8*32*32*64 threads
  int k = id & 63;
  int o = (id >> 6) & 31;
  int i = (id >> 11) & 31;
  int e = id >> 16;
  float lam = fminf(fmaxf(fw[k] * (1.0f / 6.0f) + 0.5f, 0.0f), 1.0f);
  float are = 0.f, aim = 0.f;
#pragma unroll
  for (int c = 0; c < 16; ++c) {
    float cd = codes[e * 16 + c];
    const float* p = codew + ((((c * 32 + i) * 32 + o) * 64 + k) << 1);
    are += cd * p[0];
    aim += cd * p[1];
  }
  const float* q = comw + (((i * 32 + o) * 64 + k) << 1);
  float* dst = W + ((((e * 32 + i) * 32 + o) * 64 + k) << 1);
  dst[0] = lam * q[0] + (1.f - lam) * are;
  dst[1] = lam * q[1] + (1.f - lam) * aim;
}

// ---------------------------------------------------------------------------
// Stage 1: Xp[sp][4096][128] = x[.,slab] * B1t^T   (split-K, NO atomics)
// grid (128 m-tiles of 32 rows, 8 splits of 1024 cols). 4 waves;
// wave-tile M=32 x N=32 (wave w owns n-slice w*32). BK=256 chunks (4).
// A staged via LDS: each wave-load instr = 1 KB CONTIGUOUS from ONE x-row
// (the DRAM-efficiency fix). B1t (2 MB, L2-hot) read direct per-fragment.
// LDS pitch 264 bf16 -> 2-way banks on b128 frag reads (free).
// ---------------------------------------------------------------------------
__global__ __launch_bounds__(256) void stage1(const float* __restrict__ x,
                                              const bf16_t* __restrict__ B1t,
                                              float* __restrict__ Xp) {
  __shared__ bf16_t Al[32 * 264];   // 16.9 KiB
  const int t = threadIdx.x;
  const int lane = t & 63;
  const int w = t >> 6;
  const int lq = lane >> 4, l15 = lane & 15;
  const int mt = blockIdx.x, sp = blockIdx.y;
  const int mbase = mt * 32;
  const int wv = t >> 6, ln = t & 63;

  f32x4 acc[2][2];
#pragma unroll
  for (int a = 0; a < 2; ++a)
#pragma unroll
    for (int b = 0; b < 2; ++b) acc[a][b] = (f32x4){0.f, 0.f, 0.f, 0.f};

  for (int ch = 0; ch < 4; ++ch) {
    const int k0 = sp * 1024 + ch * 256;
    // prefetch: 8 rounds, each wave instr reads 1 KB contiguous from one row
    float4 xv[8];
#pragma unroll
    for (int rr = 0; rr < 8; ++rr)
      xv[rr] = *(const float4*)(x + (size_t)(mbase + rr * 4 + wv) * L_LEN + k0 + ln * 4);
    __syncthreads();   // protect prev-chunk frag reads
#pragma unroll
    for (int rr = 0; rr < 8; ++rr) {
      bf16x4v v = {(bf16_t)xv[rr].x, (bf16_t)xv[rr].y, (bf16_t)xv[rr].z, (bf16_t)xv[rr].w};
      *(bf16x4v*)(Al + (rr * 4 + wv) * 264 + ln * 4) = v;
    }
    __syncthreads();
    // 8 k-steps x (2 mf x 2 nf) MFMA
#pragma unroll
    for (int s = 0; s < 8; ++s) {
      bf16x8 a[2], b[2];
#pragma unroll
      for (int mf = 0; mf < 2; ++mf)
        a[mf] = *(const bf16x8*)(Al + (mf * 16 + l15) * 264 + s * 32 + lq * 8);
#pragma unroll
      for (int nf = 0; nf < 2; ++nf)
        b[nf] = *(const bf16x8*)(B1t + (size_t)(w * 32 + nf * 16 + l15) * L_LEN + k0 + s * 32 + lq * 8);
#pragma unroll
      for (int mf = 0; mf < 2; ++mf)
#pragma unroll
        for (int nf = 0; nf < 2; ++nf)
          acc[mf][nf] = __builtin_amdgcn_mfma_f32_16x16x32_bf16(a[mf], b[nf], acc[mf][nf], 0, 0, 0);
    }
  }
  // plain coalesced stores into this split's private slice
  float* xout = Xp + ((size_t)sp << 19);   // sp * 4096*128
#pragma unroll
  for (int mf = 0; mf < 2; ++mf)
#pragma unroll
    for (int nf = 0; nf < 2; ++nf) {
      int n = w * 32 + nf * 16 + l15;
#pragma unroll
      for (int rg = 0; rg < 4; ++rg) {
        int m = mbase + mf * 16 + lq * 4 + rg;   // C frag: row=(lane>>4)*4+reg, col=lane&15
        xout[(size_t)m * NCOMP + n] = acc[mf][nf][rg];
      }
    }
}

// ---------------------------------------------------------------------------
// Mix: per (b,e) block. Reduce the 8 split slices, then
// Y[b,e,o,k] = sum_i X[b,e,i,k]*W[e,i,o,k], irfft-scaled, bf16 A2 out.
// ---------------------------------------------------------------------------
__global__ __launch_bounds__(256) void mixk(const float* __restrict__ Xp,
                                            const float* __restrict__ W,
                                            bf16_t* __restrict__ A2) {
  __shared__ float Xs[32 * 128];
  const int t = threadIdx.x;
  const int be = blockIdx.x;       // b*8+e ; rows be*32..+32
  const int e = be & 7;
#pragma unroll
  for (int j = 0; j < 4; ++j) {
    f32x4 a = (f32x4){0.f, 0.f, 0.f, 0.f};
#pragma unroll
    for (int sp = 0; sp < NSPLIT; ++sp)
      a += *(const f32x4*)(Xp + ((size_t)sp << 19) + (size_t)be * 4096 + (t + j * 256) * 4);
    *(f32x4*)(Xs + (t + j * 256) * 4) = a;
  }
  __syncthreads();
  const int k = t & 63;
  const int olo = t >> 6;          // o = olo*8 + j
  float yre[8], yim[8];
#pragma unroll
  for (int j = 0; j < 8; ++j) { yre[j] = 0.f; yim[j] = 0.f; }
  for (int i = 0; i < 32; ++i) {
    float xr = Xs[i * 128 + k];
    float xi = Xs[i * 128 + 64 + k];
    const float* wp = W + ((((e * 32 + i) * 32 + olo * 8) * 64 + k) << 1);
#pragma unroll
    for (int j = 0; j < 8; ++j) {
      float2 wv = *(const float2*)(wp + j * 128);
      yre[j] += xr * wv.x - xi * wv.y;
      yim[j] += xr * wv.y + xi * wv.x;
    }
  }
  float sc = (k == 0) ? (1.0f / 8192.0f) : (2.0f / 8192.0f);  // irfft: DC 1/L, others 2/L
#pragma unroll
  for (int j = 0; j < 8; ++j) {
    int m = be * 32 + olo * 8 + j;
    A2[m * NCOMP + k]         = (bf16_t)(yre[j] * sc);
    A2[m * NCOMP + MODES + k] = (bf16_t)(yim[j] * sc);
  }
}

// ---------------------------------------------------------------------------
// Stage 2: out[4096][8192] = A2[4096][128] * B1^T.  Block tile 64m x 256l,
// 4 waves each 64m x 64l. Operands direct from global (A2 1 MB + B1 2 MB,
// L2-resident). Epilogue transposes through LDS so every global write instr
// is 1 KB contiguous in one out-row (the write-segment fix).
// ---------------------------------------------------------------------------
__global__ __launch_bounds__(256) void stage2(const bf16_t* __restrict__ A2,
                                              const bf16_t* __restrict__ B1,
                                              float* __restrict__ out) {
  __shared__ float Es[32 * 260];   // 33.3 KiB, pitch 260 f32 -> 2-way banks
  const int t = threadIdx.x;
  const int lane = t & 63;
  const int w = t >> 6;
  const int lt = blockIdx.x, mt = blockIdx.y;
  const int lq = lane >> 4, l15 = lane & 15;
  const int ln = t & 63;

  f32x4 acc[4][4];
#pragma unroll
  for (int a = 0; a < 4; ++a)
#pragma unroll
    for (int b = 0; b < 4; ++b) acc[a][b] = (f32x4){0.f, 0.f, 0.f, 0.f};

  const bf16_t* ap0 = A2 + (size_t)(mt * 64 + l15) * NCOMP + lq * 8;
  const bf16_t* bp0 = B1 + (size_t)(lt * 256 + w * 64 + l15) * NCOMP + lq * 8;

#pragma unroll 2
  for (int s = 0; s < 4; ++s) {
    bf16x8 a[4], b[4];
#pragma unroll
    for (int mf = 0; mf < 4; ++mf)
      a[mf] = *(const bf16x8*)(ap0 + mf * 16 * NCOMP + s * 32);
#pragma unroll
    for (int nf = 0; nf < 4; ++nf)
      b[nf] = *(const bf16x8*)(bp0 + nf * 16 * NCOMP + s * 32);
#pragma unroll
    for (int mf = 0; mf < 4; ++mf)
#pragma unroll
      for (int nf = 0; nf < 4; ++nf)
        acc[mf][nf] = __builtin_amdgcn_mfma_f32_16x16x32_bf16(a[mf], b[nf], acc[mf][nf], 0, 0, 0);
  }

  // epilogue: two half-tiles of 32 rows through LDS, then 1 KB/row stores
#pragma unroll
  for (int h = 0; h < 2; ++h) {
    __syncthreads();
#pragma unroll
    for (int mm = 0; mm < 2; ++mm) {
      int mf = 2 * h + mm;
#pragma unroll
      for (int nf = 0; nf < 4; ++nf)
#pragma unroll
        for (int rg = 0; rg < 4; ++rg)
          Es[(mm * 16 + lq * 4 + rg) * 260 + w * 64 + nf * 16 + l15] = acc[mf][nf][rg];
    }
    __syncthreads();
#pragma unroll
    for (int rr = 0; rr < 8; ++rr) {
      int row = rr * 4 + w;
      f32x4 v = *(const f32x4*)(Es + row * 260 + ln * 4);
      *(f32x4*)(out + (size_t)(mt * 64 + h * 32 + row) * L_LEN + lt * 256 + ln * 4) = v;
    }
  }
}

// ---------------------------------------------------------------------------
// ws layout:  [0,2M) B1t bf16 [128][8192]
//             [2M,4M) B1 bf16 [8192][128]
//             [4M,20M) Xp fp32 [8][4096][128]
//             [20M,24M) W fp32 [8][32][32][64][2]
//             [24M,25M) A2 bf16 [4096][128]
// ---------------------------------------------------------------------------
extern "C" void kernel_launch(void* const* d_in, const int* in_sizes, int n_in,
                              void* d_out, int out_size, void* d_ws, size_t ws_size,
                              hipStream_t stream) {
  const float* x     = (const float*)d_in[0];
  const float* codes = (const float*)d_in[1];
  const float* comw  = (const float*)d_in[2];
  const float* codew = (const float*)d_in[3];
  const float* fw    = (const float*)d_in[4];
  float* out = (float*)d_out;
  char* ws = (char*)d_ws;
  bf16_t* B1t = (bf16_t*)(ws);
  bf16_t* B1  = (bf16_t*)(ws + (size_t)(2u << 20));
  float*  Xp  = (float*) (ws + (size_t)(4u << 20));
  float*  W   = (float*) (ws + (size_t)(20u << 20));
  bf16_t* A2  = (bf16_t*)(ws + (size_t)(24u << 20));

  gen_b1 <<<2048, 256, 0, stream>>>(B1);
  gen_b1t<<<512, 256, 0, stream>>>(B1t);
  wmix<<<2048, 256, 0, stream>>>(codes, comw, codew, fw, W);
  stage1<<<dim3(128, NSPLIT), 256, 0, stream>>>(x, B1t, Xp);
  mixk<<<128, 256, 0, stream>>>(Xp, W, A2);
  stage2<<<dim3(32, 64), 256, 0, stream>>>(A2, B1, out);
}